// Round 1
// baseline (276.448 us; speedup 1.0000x reference)
//
#include <hip/hip_runtime.h>
#include <hip/hip_bf16.h>

typedef __attribute__((ext_vector_type(8))) short bf16x8;
typedef __attribute__((ext_vector_type(4))) float f32x4;

#define DEV static __device__ __forceinline__

DEV unsigned short f2bf(float f) {
    union { __hip_bfloat16 h; unsigned short u; } cv;
    cv.h = __float2bfloat16(f);
    return cv.u;
}

typedef __attribute__((address_space(1))) const void gas_t;
typedef __attribute__((address_space(3))) void las_t;

DEV void gl_lds16(const unsigned short* g, unsigned short* l) {
    __builtin_amdgcn_global_load_lds((gas_t*)g, (las_t*)l, 16, 0, 0);
}

// ---------------------------------------------------------------------------
// Kernel 1: W [3][512][512] fp32 -> WT [3][512][512] bf16, transposed so the
// contraction dim (k) is fastest. W0 pre-scaled by 1/sqrt(512).
// ---------------------------------------------------------------------------
__global__ __launch_bounds__(256, 2) void wt_kernel(const float* __restrict__ W,
                                                    unsigned short* __restrict__ WT) {
    __shared__ __align__(16) unsigned short T[64][72];
    int bid = blockIdx.x;
    int w = bid >> 6;
    int rem = bid & 63;
    int kt = rem >> 3, nt = rem & 7;
    int t = threadIdx.x;
    int r = t >> 2, cq = t & 3;
    const float* src = W + ((size_t)(w * 512 + kt * 64 + r)) * 512 + nt * 64 + cq * 16;
    float sc = (w == 0) ? 0.04419417382415922f : 1.0f;  // 1/sqrt(512)
    #pragma unroll
    for (int i = 0; i < 4; i++) {
        float4 f = *(const float4*)(src + 4 * i);
        T[r][cq * 16 + 4 * i + 0] = f2bf(f.x * sc);
        T[r][cq * 16 + 4 * i + 1] = f2bf(f.y * sc);
        T[r][cq * 16 + 4 * i + 2] = f2bf(f.z * sc);
        T[r][cq * 16 + 4 * i + 3] = f2bf(f.w * sc);
    }
    __syncthreads();
    int n = t >> 2, kq = t & 3;
    bf16x8 v0, v1;
    #pragma unroll
    for (int e = 0; e < 8; e++) v0[e] = (short)T[kq * 16 + e][n];
    #pragma unroll
    for (int e = 0; e < 8; e++) v1[e] = (short)T[kq * 16 + 8 + e][n];
    unsigned short* dst = WT + ((size_t)(w * 512 + nt * 64 + n)) * 512 + kt * 64 + kq * 16;
    *(bf16x8*)dst = v0;
    *(bf16x8*)(dst + 8) = v1;
}

// ---------------------------------------------------------------------------
// Kernel 2: QKV projection (unchanged). Outputs Q,K row-major bf16;
// V transposed to VT [8][512][2048] bf16.
// ---------------------------------------------------------------------------
__global__ __launch_bounds__(256, 2) void proj_kernel(const float* __restrict__ x,
        const unsigned short* __restrict__ WT,
        unsigned short* __restrict__ Qo, unsigned short* __restrict__ Ko,
        unsigned short* __restrict__ VTo) {
    __shared__ __align__(16) unsigned short As[128][40];
    __shared__ __align__(16) unsigned short Bs[128][40];
    __shared__ __align__(16) unsigned short Cs[128][132];

    int bid = blockIdx.x;
    int swz = (bid & 7) * 192 + (bid >> 3);
    int mt = swz / 12;
    int rem = swz - mt * 12;
    int w = rem >> 2, nt = rem & 3;
    int tid = threadIdx.x;
    int lane = tid & 63, wid = tid >> 6;
    int wm = wid >> 1, wn = wid & 1;
    int c = lane & 15, g = lane >> 4;

    const f32x4 fz = {0.f, 0.f, 0.f, 0.f};
    f32x4 acc[4][4];
    #pragma unroll
    for (int i = 0; i < 4; i++)
        #pragma unroll
        for (int j = 0; j < 4; j++) acc[i][j] = fz;

    int srow = tid >> 1, kh = tid & 1;
    const float* xp = x + (size_t)(mt * 128 + srow) * 512 + kh * 16;
    const unsigned short* wp = WT + ((size_t)(w * 512 + nt * 128 + srow)) * 512 + kh * 16;

    for (int kk = 0; kk < 16; kk++) {
        {
            const float* p = xp + kk * 32;
            float4 f0 = *(const float4*)(p);
            float4 f1 = *(const float4*)(p + 4);
            float4 f2 = *(const float4*)(p + 8);
            float4 f3 = *(const float4*)(p + 12);
            bf16x8 u0, u1;
            u0[0] = (short)f2bf(f0.x); u0[1] = (short)f2bf(f0.y);
            u0[2] = (short)f2bf(f0.z); u0[3] = (short)f2bf(f0.w);
            u0[4] = (short)f2bf(f1.x); u0[5] = (short)f2bf(f1.y);
            u0[6] = (short)f2bf(f1.z); u0[7] = (short)f2bf(f1.w);
            u1[0] = (short)f2bf(f2.x); u1[1] = (short)f2bf(f2.y);
            u1[2] = (short)f2bf(f2.z); u1[3] = (short)f2bf(f2.w);
            u1[4] = (short)f2bf(f3.x); u1[5] = (short)f2bf(f3.y);
            u1[6] = (short)f2bf(f3.z); u1[7] = (short)f2bf(f3.w);
            *(bf16x8*)&As[srow][kh * 16] = u0;
            *(bf16x8*)&As[srow][kh * 16 + 8] = u1;
            const unsigned short* q = wp + kk * 32;
            *(bf16x8*)&Bs[srow][kh * 16] = *(const bf16x8*)q;
            *(bf16x8*)&Bs[srow][kh * 16 + 8] = *(const bf16x8*)(q + 8);
        }
        __syncthreads();
        bf16x8 a[4], bb[4];
        #pragma unroll
        for (int rt = 0; rt < 4; rt++) a[rt] = *(const bf16x8*)&As[wm * 64 + rt * 16 + c][g * 8];
        #pragma unroll
        for (int ct = 0; ct < 4; ct++) bb[ct] = *(const bf16x8*)&Bs[wn * 64 + ct * 16 + c][g * 8];
        #pragma unroll
        for (int rt = 0; rt < 4; rt++)
            #pragma unroll
            for (int ct = 0; ct < 4; ct++)
                acc[rt][ct] = __builtin_amdgcn_mfma_f32_16x16x32_bf16(a[rt], bb[ct], acc[rt][ct], 0, 0, 0);
        __syncthreads();
    }

    if (w < 2) {
        unsigned short* dst = (w == 0) ? Qo : Ko;
        #pragma unroll
        for (int rt = 0; rt < 4; rt++)
            #pragma unroll
            for (int ct = 0; ct < 4; ct++)
                #pragma unroll
                for (int r = 0; r < 4; r++) {
                    int grow = mt * 128 + wm * 64 + rt * 16 + g * 4 + r;
                    int gcol = nt * 128 + wn * 64 + ct * 16 + c;
                    dst[(size_t)grow * 512 + gcol] = f2bf(acc[rt][ct][r]);
                }
    } else {
        #pragma unroll
        for (int rt = 0; rt < 4; rt++)
            #pragma unroll
            for (int ct = 0; ct < 4; ct++)
                #pragma unroll
                for (int r = 0; r < 4; r++)
                    Cs[wm * 64 + rt * 16 + g * 4 + r][wn * 64 + ct * 16 + c] = f2bf(acc[rt][ct][r]);
        __syncthreads();
        int dcol = tid >> 1, sh = tid & 1;
        int bb2 = mt >> 4;
        int s0r = (mt & 15) * 128;
        #pragma unroll
        for (int jj = 0; jj < 8; jj++) {
            bf16x8 v;
            #pragma unroll
            for (int e = 0; e < 8; e++) v[e] = (short)Cs[sh * 64 + jj * 8 + e][dcol];
            *(bf16x8*)(VTo + ((size_t)(bb2 * 512 + nt * 128 + dcol)) * 2048 + s0r + sh * 64 + jj * 8) = v;
        }
    }
}

// ---------------------------------------------------------------------------
// Kernel 3 (v3): flash attention, no-max softmax. SAME data paths as v2
// (K DMA w/ XOR-swizzle, V direct from L2, Ps round-trip, 2 barriers/tile)
// but remapped to a 1024-thread / 16-wave block so 4 waves/SIMD are resident
// (v2's 512-thr layout needed qf[2][16]+o[4][4] = ~190 VGPR -> capped at
// 2 waves/SIMD). Now each score wave owns ONE 16q x 16kv S-tile
// (qf[16] = 64 VGPR, one f32x4 acc) and each PV wave owns 32 d-cols
// (o[4][2] = 32 VGPR) -> fits the 128-reg budget 4 waves/SIMD requires.
// ---------------------------------------------------------------------------
__global__ __launch_bounds__(1024) void attn_kernel(const unsigned short* __restrict__ Qg,
        const unsigned short* __restrict__ Kg, const unsigned short* __restrict__ VTg,
        float* __restrict__ out) {
    __shared__ __align__(16) unsigned short Ks[2][64 * 512];  // 128 KB, swizzled
    __shared__ __align__(16) unsigned short Ps[64][72];       // 9.2 KB
    __shared__ float psum_s[64][4];

    int bid = blockIdx.x;
    int swz = (bid & 7) * 32 + (bid >> 3);  // XCD x owns batch x
    int b = swz >> 5, qt = swz & 31;
    int tid = threadIdx.x;
    int lane = tid & 63, wid = tid >> 6;    // wid 0..15
    int c = lane & 15, g = lane >> 4;
    int qg = wid >> 2, kg = wid & 3;        // score: 4x4 grid of 16x16 S-tiles

    const unsigned short* Qb = Qg + ((size_t)(b * 2048 + qt * 64)) * 512;
    const unsigned short* Kb = Kg + ((size_t)b * 2048) * 512;
    const unsigned short* Vb = VTg + ((size_t)b * 512) * 2048;

    // ---- stage Q (swizzled source) into Ks[0], then lift fragments to regs
    #pragma unroll
    for (int i = 0; i < 4; i++) {
        int r = wid * 4 + i;
        gl_lds16(Qb + (size_t)r * 512 + ((lane ^ (r & 7)) * 8), &Ks[0][r * 512]);
    }
    __syncthreads();  // vmcnt(0): Q DMA done

    bf16x8 qf[16];
    {
        int row = qg * 16 + c;
        #pragma unroll
        for (int ks = 0; ks < 16; ks++)
            qf[ks] = *(const bf16x8*)&Ks[0][row * 512 + (((ks * 4 + g) ^ (row & 7)) * 8)];
    }
    __syncthreads();  // Q reads done before K(0) overwrites buf0

    // ---- stage K tile 0 into buf 0
    #pragma unroll
    for (int i = 0; i < 4; i++) {
        int r = wid * 4 + i;
        gl_lds16(Kb + (size_t)r * 512 + ((lane ^ (r & 7)) * 8), &Ks[0][r * 512]);
    }

    const f32x4 fz = {0.f, 0.f, 0.f, 0.f};
    f32x4 o[4][2];
    #pragma unroll
    for (int i = 0; i < 4; i++)
        #pragma unroll
        for (int j = 0; j < 2; j++) o[i][j] = fz;
    float acc4[4];
    #pragma unroll
    for (int j = 0; j < 4; j++) acc4[j] = 0.0f;

    for (int t = 0; t < 32; t++) {
        const unsigned short* KsC = &Ks[t & 1][0];
        unsigned short* KsN = &Ks[(t + 1) & 1][0];
        __syncthreads();  // vmcnt(0)+lgkmcnt(0): K(t) staged; Ps(t-1) reads retired

        if (t + 1 < 32) {  // stage K(t+1) async; flies across this tile's barriers
            #pragma unroll
            for (int i = 0; i < 4; i++) {
                int r = wid * 4 + i;
                gl_lds16(Kb + (size_t)((t + 1) * 64 + r) * 512 + ((lane ^ (r & 7)) * 8), KsN + r * 512);
            }
        }

        // prefetch V fragments (ks2=0) — L2 latency hides under the score MFMAs
        bf16x8 bv0[2];
        #pragma unroll
        for (int ct = 0; ct < 2; ct++)
            bv0[ct] = *(const bf16x8*)(Vb + (size_t)(wid * 32 + ct * 16 + c) * 2048 + t * 64 + g * 8);

        // ---- scores: S[16q x 16kv] per wave, Q from regs, K from LDS
        f32x4 s = fz;
        int krow = kg * 16 + c;
        #pragma unroll
        for (int ks = 0; ks < 16; ks++) {
            bf16x8 bk = *(const bf16x8*)&KsC[krow * 512 + (((ks * 4 + g) ^ (krow & 7)) * 8)];
            s = __builtin_amdgcn_mfma_f32_16x16x32_bf16(qf[ks], bk, s, 0, 0, 0);
        }

        // ---- P = exp(S); write Ps (bf16); accumulate row-sums in registers
        #pragma unroll
        for (int r = 0; r < 4; r++) {
            int row = qg * 16 + g * 4 + r;
            float p = __expf(s[r]);
            acc4[r] += p;
            Ps[row][kg * 16 + c] = f2bf(p);
        }
        asm volatile("s_waitcnt lgkmcnt(0)" ::: "memory");
        __builtin_amdgcn_s_barrier();  // Ps ready; K(t+1) DMA stays in flight

        // ---- PV: O[64][32-chunk] += P[64][64] * V[64][chunk]
        bf16x8 bv1[2];
        #pragma unroll
        for (int ct = 0; ct < 2; ct++)
            bv1[ct] = *(const bf16x8*)(Vb + (size_t)(wid * 32 + ct * 16 + c) * 2048 + t * 64 + 32 + g * 8);
        #pragma unroll
        for (int rt = 0; rt < 4; rt++) {
            bf16x8 pa = *(const bf16x8*)&Ps[rt * 16 + c][g * 8];
            #pragma unroll
            for (int ct = 0; ct < 2; ct++)
                o[rt][ct] = __builtin_amdgcn_mfma_f32_16x16x32_bf16(pa, bv0[ct], o[rt][ct], 0, 0, 0);
        }
        #pragma unroll
        for (int rt = 0; rt < 4; rt++) {
            bf16x8 pa = *(const bf16x8*)&Ps[rt * 16 + c][32 + g * 8];
            #pragma unroll
            for (int ct = 0; ct < 2; ct++)
                o[rt][ct] = __builtin_amdgcn_mfma_f32_16x16x32_bf16(pa, bv1[ct], o[rt][ct], 0, 0, 0);
        }
    }

    // ---- final l reduction (once, not per-tile)
    #pragma unroll
    for (int r = 0; r < 4; r++) {
        float v = acc4[r];
        v += __shfl_xor(v, 1);
        v += __shfl_xor(v, 2);
        v += __shfl_xor(v, 4);
        v += __shfl_xor(v, 8);
        if (c == 0) psum_s[qg * 16 + g * 4 + r][kg] = v;
    }
    __syncthreads();

    float* ob = out + ((size_t)(b * 2048 + qt * 64)) * 512;
    #pragma unroll
    for (int rt = 0; rt < 4; rt++)
        #pragma unroll
        for (int r = 0; r < 4; r++) {
            int lrow = rt * 16 + g * 4 + r;
            float l = psum_s[lrow][0] + psum_s[lrow][1] + psum_s[lrow][2] + psum_s[lrow][3];
            float inv = 1.0f / l;
            #pragma unroll
            for (int ct = 0; ct < 2; ct++)
                ob[(size_t)lrow * 512 + wid * 32 + ct * 16 + c] = o[rt][ct][r] * inv;
        }
}

// ---------------------------------------------------------------------------
extern "C" void kernel_launch(void* const* d_in, const int* in_sizes, int n_in,
                              void* d_out, int out_size, void* d_ws, size_t ws_size,
                              hipStream_t stream) {
    const float* x = (const float*)d_in[0];   // [8][2048][512] fp32
    const float* W = (const float*)d_in[1];   // [3][512][512] fp32
    float* out = (float*)d_out;               // [8][2048][512] fp32
    char* ws = (char*)d_ws;
    unsigned short* WT = (unsigned short*)(ws);
    unsigned short* Q  = (unsigned short*)(ws + (size_t)2  * 1024 * 1024);
    unsigned short* K  = (unsigned short*)(ws + (size_t)18 * 1024 * 1024);
    unsigned short* VT = (unsigned short*)(ws + (size_t)34 * 1024 * 1024);

    wt_kernel<<<192, 256, 0, stream>>>(W, WT);
    proj_kernel<<<1536, 256, 0, stream>>>(x, WT, Q, K, VT);
    attn_kernel<<<256, 1024, 0, stream>>>(Q, K, VT, out);
}

// Round 3
// 230.429 us; speedup vs baseline: 1.1997x; 1.1997x over previous
//
#include <hip/hip_runtime.h>
#include <hip/hip_bf16.h>

typedef __attribute__((ext_vector_type(8))) short bf16x8;
typedef __attribute__((ext_vector_type(4))) float f32x4;

#define DEV static __device__ __forceinline__

DEV unsigned short f2bf(float f) {
    union { __hip_bfloat16 h; unsigned short u; } cv;
    cv.h = __float2bfloat16(f);
    return cv.u;
}

typedef __attribute__((address_space(1))) const void gas_t;
typedef __attribute__((address_space(3))) void las_t;

DEV void gl_lds16(const unsigned short* g, unsigned short* l) {
    __builtin_amdgcn_global_load_lds((gas_t*)g, (las_t*)l, 16, 0, 0);
}

// ---------------------------------------------------------------------------
// Kernel 1: W [3][512][512] fp32 -> WT [3][512][512] bf16, transposed so the
// contraction dim (k) is fastest. W0 pre-scaled by 1/sqrt(512).
// ---------------------------------------------------------------------------
__global__ __launch_bounds__(256, 2) void wt_kernel(const float* __restrict__ W,
                                                    unsigned short* __restrict__ WT) {
    __shared__ __align__(16) unsigned short T[64][72];
    int bid = blockIdx.x;
    int w = bid >> 6;
    int rem = bid & 63;
    int kt = rem >> 3, nt = rem & 7;
    int t = threadIdx.x;
    int r = t >> 2, cq = t & 3;
    const float* src = W + ((size_t)(w * 512 + kt * 64 + r)) * 512 + nt * 64 + cq * 16;
    float sc = (w == 0) ? 0.04419417382415922f : 1.0f;  // 1/sqrt(512)
    #pragma unroll
    for (int i = 0; i < 4; i++) {
        float4 f = *(const float4*)(src + 4 * i);
        T[r][cq * 16 + 4 * i + 0] = f2bf(f.x * sc);
        T[r][cq * 16 + 4 * i + 1] = f2bf(f.y * sc);
        T[r][cq * 16 + 4 * i + 2] = f2bf(f.z * sc);
        T[r][cq * 16 + 4 * i + 3] = f2bf(f.w * sc);
    }
    __syncthreads();
    int n = t >> 2, kq = t & 3;
    bf16x8 v0, v1;
    #pragma unroll
    for (int e = 0; e < 8; e++) v0[e] = (short)T[kq * 16 + e][n];
    #pragma unroll
    for (int e = 0; e < 8; e++) v1[e] = (short)T[kq * 16 + 8 + e][n];
    unsigned short* dst = WT + ((size_t)(w * 512 + nt * 64 + n)) * 512 + kt * 64 + kq * 16;
    *(bf16x8*)dst = v0;
    *(bf16x8*)(dst + 8) = v1;
}

// ---------------------------------------------------------------------------
// Kernel 2: QKV projection (unchanged). Outputs Q,K row-major bf16;
// V transposed to VT [8][512][2048] bf16.
// ---------------------------------------------------------------------------
__global__ __launch_bounds__(256, 2) void proj_kernel(const float* __restrict__ x,
        const unsigned short* __restrict__ WT,
        unsigned short* __restrict__ Qo, unsigned short* __restrict__ Ko,
        unsigned short* __restrict__ VTo) {
    __shared__ __align__(16) unsigned short As[128][40];
    __shared__ __align__(16) unsigned short Bs[128][40];
    __shared__ __align__(16) unsigned short Cs[128][132];

    int bid = blockIdx.x;
    int swz = (bid & 7) * 192 + (bid >> 3);
    int mt = swz / 12;
    int rem = swz - mt * 12;
    int w = rem >> 2, nt = rem & 3;
    int tid = threadIdx.x;
    int lane = tid & 63, wid = tid >> 6;
    int wm = wid >> 1, wn = wid & 1;
    int c = lane & 15, g = lane >> 4;

    const f32x4 fz = {0.f, 0.f, 0.f, 0.f};
    f32x4 acc[4][4];
    #pragma unroll
    for (int i = 0; i < 4; i++)
        #pragma unroll
        for (int j = 0; j < 4; j++) acc[i][j] = fz;

    int srow = tid >> 1, kh = tid & 1;
    const float* xp = x + (size_t)(mt * 128 + srow) * 512 + kh * 16;
    const unsigned short* wp = WT + ((size_t)(w * 512 + nt * 128 + srow)) * 512 + kh * 16;

    for (int kk = 0; kk < 16; kk++) {
        {
            const float* p = xp + kk * 32;
            float4 f0 = *(const float4*)(p);
            float4 f1 = *(const float4*)(p + 4);
            float4 f2 = *(const float4*)(p + 8);
            float4 f3 = *(const float4*)(p + 12);
            bf16x8 u0, u1;
            u0[0] = (short)f2bf(f0.x); u0[1] = (short)f2bf(f0.y);
            u0[2] = (short)f2bf(f0.z); u0[3] = (short)f2bf(f0.w);
            u0[4] = (short)f2bf(f1.x); u0[5] = (short)f2bf(f1.y);
            u0[6] = (short)f2bf(f1.z); u0[7] = (short)f2bf(f1.w);
            u1[0] = (short)f2bf(f2.x); u1[1] = (short)f2bf(f2.y);
            u1[2] = (short)f2bf(f2.z); u1[3] = (short)f2bf(f2.w);
            u1[4] = (short)f2bf(f3.x); u1[5] = (short)f2bf(f3.y);
            u1[6] = (short)f2bf(f3.z); u1[7] = (short)f2bf(f3.w);
            *(bf16x8*)&As[srow][kh * 16] = u0;
            *(bf16x8*)&As[srow][kh * 16 + 8] = u1;
            const unsigned short* q = wp + kk * 32;
            *(bf16x8*)&Bs[srow][kh * 16] = *(const bf16x8*)q;
            *(bf16x8*)&Bs[srow][kh * 16 + 8] = *(const bf16x8*)(q + 8);
        }
        __syncthreads();
        bf16x8 a[4], bb[4];
        #pragma unroll
        for (int rt = 0; rt < 4; rt++) a[rt] = *(const bf16x8*)&As[wm * 64 + rt * 16 + c][g * 8];
        #pragma unroll
        for (int ct = 0; ct < 4; ct++) bb[ct] = *(const bf16x8*)&Bs[wn * 64 + ct * 16 + c][g * 8];
        #pragma unroll
        for (int rt = 0; rt < 4; rt++)
            #pragma unroll
            for (int ct = 0; ct < 4; ct++)
                acc[rt][ct] = __builtin_amdgcn_mfma_f32_16x16x32_bf16(a[rt], bb[ct], acc[rt][ct], 0, 0, 0);
        __syncthreads();
    }

    if (w < 2) {
        unsigned short* dst = (w == 0) ? Qo : Ko;
        #pragma unroll
        for (int rt = 0; rt < 4; rt++)
            #pragma unroll
            for (int ct = 0; ct < 4; ct++)
                #pragma unroll
                for (int r = 0; r < 4; r++) {
                    int grow = mt * 128 + wm * 64 + rt * 16 + g * 4 + r;
                    int gcol = nt * 128 + wn * 64 + ct * 16 + c;
                    dst[(size_t)grow * 512 + gcol] = f2bf(acc[rt][ct][r]);
                }
    } else {
        #pragma unroll
        for (int rt = 0; rt < 4; rt++)
            #pragma unroll
            for (int ct = 0; ct < 4; ct++)
                #pragma unroll
                for (int r = 0; r < 4; r++)
                    Cs[wm * 64 + rt * 16 + g * 4 + r][wn * 64 + ct * 16 + c] = f2bf(acc[rt][ct][r]);
        __syncthreads();
        int dcol = tid >> 1, sh = tid & 1;
        int bb2 = mt >> 4;
        int s0r = (mt & 15) * 128;
        #pragma unroll
        for (int jj = 0; jj < 8; jj++) {
            bf16x8 v;
            #pragma unroll
            for (int e = 0; e < 8; e++) v[e] = (short)Cs[sh * 64 + jj * 8 + e][dcol];
            *(bf16x8*)(VTo + ((size_t)(bb2 * 512 + nt * 128 + dcol)) * 2048 + s0r + sh * 64 + jj * 8) = v;
        }
    }
}

// ---------------------------------------------------------------------------
// Kernel 3 (v5): producer-consumer flash attention.
// 16 waves: wid 0..7 = score waves (hold Q fragments, compute S->exp->Ps),
// wid 8..15 = PV waves (hold O accumulators, consume Ps(t-1) with V(t-1)).
// One barrier per tile; one-tile software pipeline; Ps double-buffered.
// qf (score-only) and o (PV-only) share ONE f32x4 st[16] array (bit-cast
// views) so the static register budget stays under the 128-reg / 4-wave cap.
// ---------------------------------------------------------------------------
__global__ __launch_bounds__(1024, 4) void attn_kernel(const unsigned short* __restrict__ Qg,
        const unsigned short* __restrict__ Kg, const unsigned short* __restrict__ VTg,
        float* __restrict__ out) {
    __shared__ __align__(16) unsigned short Ks[2][64 * 512];  // 128 KB, swizzled
    __shared__ __align__(16) unsigned short Ps[2][64][72];    // 18.4 KB, dbuf
    __shared__ float psum_s[64][2];

    int bid = blockIdx.x;
    int swz = (bid & 7) * 32 + (bid >> 3);  // XCD x owns batch x
    int b = swz >> 5, qt = swz & 31;
    int tid = threadIdx.x;
    int lane = tid & 63, wid = tid >> 6;    // wid 0..15
    int c = lane & 15, g = lane >> 4;

    bool is_score = (wid < 8);
    int sqg = wid >> 1;          // score: q-row group (0..3), two waves each
    int skg = (wid & 1) * 2;     // score: first of two 16-col kv groups (0 or 2)
    int pcol = (wid - 8) * 64;   // PV: d-column base (0..448)

    const unsigned short* Qb = Qg + ((size_t)(b * 2048 + qt * 64)) * 512;
    const unsigned short* Kb = Kg + ((size_t)b * 2048) * 512;
    const unsigned short* Vb = VTg + ((size_t)b * 512) * 2048;

    // ---- stage Q (swizzled source) into Ks[0]
    #pragma unroll
    for (int i = 0; i < 4; i++) {
        int r = wid * 4 + i;
        gl_lds16(Qb + (size_t)r * 512 + ((lane ^ (r & 7)) * 8), &Ks[0][r * 512]);
    }
    __syncthreads();  // vmcnt(0): Q DMA done

    // st = union{ score: qf[16] (bf16x8 views) | PV: o[4][4] accumulators }
    f32x4 st[16];
    float accs[8];
    if (is_score) {
        int row = sqg * 16 + c;
        #pragma unroll
        for (int ks = 0; ks < 16; ks++)
            st[ks] = __builtin_bit_cast(f32x4,
                *(const bf16x8*)&Ks[0][row * 512 + (((ks * 4 + g) ^ (row & 7)) * 8)]);
    } else {
        const f32x4 fz = {0.f, 0.f, 0.f, 0.f};
        #pragma unroll
        for (int i = 0; i < 16; i++) st[i] = fz;
    }
    #pragma unroll
    for (int j = 0; j < 8; j++) accs[j] = 0.0f;
    __syncthreads();  // Q reads done before K(0) overwrites buf0

    // ---- stage K tile 0 into buf 0
    #pragma unroll
    for (int i = 0; i < 4; i++) {
        int r = wid * 4 + i;
        gl_lds16(Kb + (size_t)r * 512 + ((lane ^ (r & 7)) * 8), &Ks[0][r * 512]);
    }

    auto pv_step = [&](int tp) {
        const unsigned short* PsR = &Ps[tp & 1][0][0];
        bf16x8 bv[8];
        #pragma unroll
        for (int h = 0; h < 2; h++)
            #pragma unroll
            for (int ct = 0; ct < 4; ct++)
                bv[h * 4 + ct] = *(const bf16x8*)(Vb +
                    (size_t)(pcol + ct * 16 + c) * 2048 + tp * 64 + h * 32 + g * 8);
        #pragma unroll
        for (int h = 0; h < 2; h++)
            #pragma unroll
            for (int rt = 0; rt < 4; rt++) {
                bf16x8 pa = *(const bf16x8*)&PsR[(rt * 16 + c) * 72 + h * 32 + g * 8];
                #pragma unroll
                for (int ct = 0; ct < 4; ct++)
                    st[rt * 4 + ct] = __builtin_amdgcn_mfma_f32_16x16x32_bf16(
                        pa, bv[h * 4 + ct], st[rt * 4 + ct], 0, 0, 0);
            }
    };

    for (int t = 0; t < 32; t++) {
        __syncthreads();  // K(t) staged (vmcnt0); Ps(t-1) visible; Ps(t)-buf reads retired

        if (t + 1 < 32) {  // all waves stage K(t+1); DMA flies across this tile
            #pragma unroll
            for (int i = 0; i < 4; i++) {
                int r = wid * 4 + i;
                gl_lds16(Kb + (size_t)((t + 1) * 64 + r) * 512 + ((lane ^ (r & 7)) * 8),
                         &Ks[(t + 1) & 1][r * 512]);
            }
        }

        if (is_score) {
            const unsigned short* KsC = &Ks[t & 1][0];
            const f32x4 fz = {0.f, 0.f, 0.f, 0.f};
            f32x4 s0 = fz, s1 = fz;
            int kr0 = skg * 16 + c;
            int kr1 = kr0 + 16;
            #pragma unroll
            for (int ks = 0; ks < 16; ks++) {
                bf16x8 qv = __builtin_bit_cast(bf16x8, st[ks]);
                bf16x8 bk0 = *(const bf16x8*)&KsC[kr0 * 512 + (((ks * 4 + g) ^ (kr0 & 7)) * 8)];
                bf16x8 bk1 = *(const bf16x8*)&KsC[kr1 * 512 + (((ks * 4 + g) ^ (kr1 & 7)) * 8)];
                s0 = __builtin_amdgcn_mfma_f32_16x16x32_bf16(qv, bk0, s0, 0, 0, 0);
                s1 = __builtin_amdgcn_mfma_f32_16x16x32_bf16(qv, bk1, s1, 0, 0, 0);
            }
            unsigned short* PsW = &Ps[t & 1][0][0];
            #pragma unroll
            for (int r = 0; r < 4; r++) {
                int row = sqg * 16 + g * 4 + r;
                float p0 = __expf(s0[r]);
                float p1 = __expf(s1[r]);
                accs[r] += p0;
                accs[4 + r] += p1;
                PsW[row * 72 + skg * 16 + c] = f2bf(p0);
                PsW[row * 72 + (skg + 1) * 16 + c] = f2bf(p1);
            }
        } else if (t > 0) {
            pv_step(t - 1);
        }
    }

    // ---- score waves: final row-sum reduction into psum_s
    if (is_score) {
        #pragma unroll
        for (int r = 0; r < 4; r++) {
            float v = accs[r] + accs[4 + r];  // both kv-col groups of this wave
            v += __shfl_xor(v, 1);
            v += __shfl_xor(v, 2);
            v += __shfl_xor(v, 4);
            v += __shfl_xor(v, 8);
            if (c == 0) psum_s[sqg * 16 + g * 4 + r][wid & 1] = v;
        }
    }
    __syncthreads();  // Ps(31) + psum_s visible

    if (!is_score) {
        pv_step(31);
        float* ob = out + ((size_t)(b * 2048 + qt * 64)) * 512;
        #pragma unroll
        for (int rt = 0; rt < 4; rt++)
            #pragma unroll
            for (int r = 0; r < 4; r++) {
                int lrow = rt * 16 + g * 4 + r;
                float l = psum_s[lrow][0] + psum_s[lrow][1];
                float inv = 1.0f / l;
                #pragma unroll
                for (int ct = 0; ct < 4; ct++)
                    ob[(size_t)lrow * 512 + pcol + ct * 16 + c] = st[rt * 4 + ct][r] * inv;
            }
    }
}

// ---------------------------------------------------------------------------
extern "C" void kernel_launch(void* const* d_in, const int* in_sizes, int n_in,
                              void* d_out, int out_size, void* d_ws, size_t ws_size,
                              hipStream_t stream) {
    const float* x = (const float*)d_in[0];   // [8][2048][512] fp32
    const float* W = (const float*)d_in[1];   // [3][512][512] fp32
    float* out = (float*)d_out;               // [8][2048][512] fp32
    char* ws = (char*)d_ws;
    unsigned short* WT = (unsigned short*)(ws);
    unsigned short* Q  = (unsigned short*)(ws + (size_t)2  * 1024 * 1024);
    unsigned short* K  = (unsigned short*)(ws + (size_t)18 * 1024 * 1024);
    unsigned short* VT = (unsigned short*)(ws + (size_t)34 * 1024 * 1024);

    wt_kernel<<<192, 256, 0, stream>>>(W, WT);
    proj_kernel<<<1536, 256, 0, stream>>>(x, WT, Q, K, VT);
    attn_kernel<<<256, 1024, 0, stream>>>(Q, K, VT, out);
}

// Round 4
// 228.306 us; speedup vs baseline: 1.2109x; 1.0093x over previous
//
#include <hip/hip_runtime.h>
#include <hip/hip_bf16.h>

typedef __attribute__((ext_vector_type(8))) short bf16x8;
typedef __attribute__((ext_vector_type(4))) float f32x4;

#define DEV static __device__ __forceinline__

DEV unsigned short f2bf(float f) {
    union { __hip_bfloat16 h; unsigned short u; } cv;
    cv.h = __float2bfloat16(f);
    return cv.u;
}

typedef __attribute__((address_space(1))) const void gas_t;
typedef __attribute__((address_space(3))) void las_t;

DEV void gl_lds16(const unsigned short* g, unsigned short* l) {
    __builtin_amdgcn_global_load_lds((gas_t*)g, (las_t*)l, 16, 0, 0);
}

// ---------------------------------------------------------------------------
// Kernel 1: W [3][512][512] fp32 -> WT [3][512][512] bf16, transposed so the
// contraction dim (k) is fastest. W0 pre-scaled by 1/sqrt(512).
// ---------------------------------------------------------------------------
__global__ __launch_bounds__(256, 2) void wt_kernel(const float* __restrict__ W,
                                                    unsigned short* __restrict__ WT) {
    __shared__ __align__(16) unsigned short T[64][72];
    int bid = blockIdx.x;
    int w = bid >> 6;
    int rem = bid & 63;
    int kt = rem >> 3, nt = rem & 7;
    int t = threadIdx.x;
    int r = t >> 2, cq = t & 3;
    const float* src = W + ((size_t)(w * 512 + kt * 64 + r)) * 512 + nt * 64 + cq * 16;
    float sc = (w == 0) ? 0.04419417382415922f : 1.0f;  // 1/sqrt(512)
    #pragma unroll
    for (int i = 0; i < 4; i++) {
        float4 f = *(const float4*)(src + 4 * i);
        T[r][cq * 16 + 4 * i + 0] = f2bf(f.x * sc);
        T[r][cq * 16 + 4 * i + 1] = f2bf(f.y * sc);
        T[r][cq * 16 + 4 * i + 2] = f2bf(f.z * sc);
        T[r][cq * 16 + 4 * i + 3] = f2bf(f.w * sc);
    }
    __syncthreads();
    int n = t >> 2, kq = t & 3;
    bf16x8 v0, v1;
    #pragma unroll
    for (int e = 0; e < 8; e++) v0[e] = (short)T[kq * 16 + e][n];
    #pragma unroll
    for (int e = 0; e < 8; e++) v1[e] = (short)T[kq * 16 + 8 + e][n];
    unsigned short* dst = WT + ((size_t)(w * 512 + nt * 64 + n)) * 512 + kt * 64 + kq * 16;
    *(bf16x8*)dst = v0;
    *(bf16x8*)(dst + 8) = v1;
}

// ---------------------------------------------------------------------------
// Kernel 2: QKV projection (unchanged). Outputs Q,K row-major bf16;
// V transposed to VT [8][512][2048] bf16.
// ---------------------------------------------------------------------------
__global__ __launch_bounds__(256, 2) void proj_kernel(const float* __restrict__ x,
        const unsigned short* __restrict__ WT,
        unsigned short* __restrict__ Qo, unsigned short* __restrict__ Ko,
        unsigned short* __restrict__ VTo) {
    __shared__ __align__(16) unsigned short As[128][40];
    __shared__ __align__(16) unsigned short Bs[128][40];
    __shared__ __align__(16) unsigned short Cs[128][132];

    int bid = blockIdx.x;
    int swz = (bid & 7) * 192 + (bid >> 3);
    int mt = swz / 12;
    int rem = swz - mt * 12;
    int w = rem >> 2, nt = rem & 3;
    int tid = threadIdx.x;
    int lane = tid & 63, wid = tid >> 6;
    int wm = wid >> 1, wn = wid & 1;
    int c = lane & 15, g = lane >> 4;

    const f32x4 fz = {0.f, 0.f, 0.f, 0.f};
    f32x4 acc[4][4];
    #pragma unroll
    for (int i = 0; i < 4; i++)
        #pragma unroll
        for (int j = 0; j < 4; j++) acc[i][j] = fz;

    int srow = tid >> 1, kh = tid & 1;
    const float* xp = x + (size_t)(mt * 128 + srow) * 512 + kh * 16;
    const unsigned short* wp = WT + ((size_t)(w * 512 + nt * 128 + srow)) * 512 + kh * 16;

    for (int kk = 0; kk < 16; kk++) {
        {
            const float* p = xp + kk * 32;
            float4 f0 = *(const float4*)(p);
            float4 f1 = *(const float4*)(p + 4);
            float4 f2 = *(const float4*)(p + 8);
            float4 f3 = *(const float4*)(p + 12);
            bf16x8 u0, u1;
            u0[0] = (short)f2bf(f0.x); u0[1] = (short)f2bf(f0.y);
            u0[2] = (short)f2bf(f0.z); u0[3] = (short)f2bf(f0.w);
            u0[4] = (short)f2bf(f1.x); u0[5] = (short)f2bf(f1.y);
            u0[6] = (short)f2bf(f1.z); u0[7] = (short)f2bf(f1.w);
            u1[0] = (short)f2bf(f2.x); u1[1] = (short)f2bf(f2.y);
            u1[2] = (short)f2bf(f2.z); u1[3] = (short)f2bf(f2.w);
            u1[4] = (short)f2bf(f3.x); u1[5] = (short)f2bf(f3.y);
            u1[6] = (short)f2bf(f3.z); u1[7] = (short)f2bf(f3.w);
            *(bf16x8*)&As[srow][kh * 16] = u0;
            *(bf16x8*)&As[srow][kh * 16 + 8] = u1;
            const unsigned short* q = wp + kk * 32;
            *(bf16x8*)&Bs[srow][kh * 16] = *(const bf16x8*)q;
            *(bf16x8*)&Bs[srow][kh * 16 + 8] = *(const bf16x8*)(q + 8);
        }
        __syncthreads();
        bf16x8 a[4], bb[4];
        #pragma unroll
        for (int rt = 0; rt < 4; rt++) a[rt] = *(const bf16x8*)&As[wm * 64 + rt * 16 + c][g * 8];
        #pragma unroll
        for (int ct = 0; ct < 4; ct++) bb[ct] = *(const bf16x8*)&Bs[wn * 64 + ct * 16 + c][g * 8];
        #pragma unroll
        for (int rt = 0; rt < 4; rt++)
            #pragma unroll
            for (int ct = 0; ct < 4; ct++)
                acc[rt][ct] = __builtin_amdgcn_mfma_f32_16x16x32_bf16(a[rt], bb[ct], acc[rt][ct], 0, 0, 0);
        __syncthreads();
    }

    if (w < 2) {
        unsigned short* dst = (w == 0) ? Qo : Ko;
        #pragma unroll
        for (int rt = 0; rt < 4; rt++)
            #pragma unroll
            for (int ct = 0; ct < 4; ct++)
                #pragma unroll
                for (int r = 0; r < 4; r++) {
                    int grow = mt * 128 + wm * 64 + rt * 16 + g * 4 + r;
                    int gcol = nt * 128 + wn * 64 + ct * 16 + c;
                    dst[(size_t)grow * 512 + gcol] = f2bf(acc[rt][ct][r]);
                }
    } else {
        #pragma unroll
        for (int rt = 0; rt < 4; rt++)
            #pragma unroll
            for (int ct = 0; ct < 4; ct++)
                #pragma unroll
                for (int r = 0; r < 4; r++)
                    Cs[wm * 64 + rt * 16 + g * 4 + r][wn * 64 + ct * 16 + c] = f2bf(acc[rt][ct][r]);
        __syncthreads();
        int dcol = tid >> 1, sh = tid & 1;
        int bb2 = mt >> 4;
        int s0r = (mt & 15) * 128;
        #pragma unroll
        for (int jj = 0; jj < 8; jj++) {
            bf16x8 v;
            #pragma unroll
            for (int e = 0; e < 8; e++) v[e] = (short)Cs[sh * 64 + jj * 8 + e][dcol];
            *(bf16x8*)(VTo + ((size_t)(bb2 * 512 + nt * 128 + dcol)) * 2048 + s0r + sh * 64 + jj * 8) = v;
        }
    }
}

// ---------------------------------------------------------------------------
// Kernel 3 (v6): v5 producer-consumer pipeline, with occupancy PINNED via
// amdgpu_waves_per_eu(4,4). v5's launch_bounds(1024,4) only set a MINIMUM;
// the backend targeted 8 waves/EU, allocated 64 VGPRs and spilled st[16]
// (WRITE_SIZE 66->139 MB = scratch). Exact 4 waves/EU -> 128-VGPR budget.
// ---------------------------------------------------------------------------
__global__
__attribute__((amdgpu_flat_work_group_size(1024, 1024), amdgpu_waves_per_eu(4, 4)))
void attn_kernel(const unsigned short* __restrict__ Qg,
        const unsigned short* __restrict__ Kg, const unsigned short* __restrict__ VTg,
        float* __restrict__ out) {
    __shared__ __align__(16) unsigned short Ks[2][64 * 512];  // 128 KB, swizzled
    __shared__ __align__(16) unsigned short Ps[2][64][72];    // 18.4 KB, dbuf
    __shared__ float psum_s[64][2];

    int bid = blockIdx.x;
    int swz = (bid & 7) * 32 + (bid >> 3);  // XCD x owns batch x
    int b = swz >> 5, qt = swz & 31;
    int tid = threadIdx.x;
    int lane = tid & 63, wid = tid >> 6;    // wid 0..15
    int c = lane & 15, g = lane >> 4;

    bool is_score = (wid < 8);
    int sqg = wid >> 1;          // score: q-row group (0..3), two waves each
    int skg = (wid & 1) * 2;     // score: first of two 16-col kv groups (0 or 2)
    int pcol = (wid - 8) * 64;   // PV: d-column base (0..448)

    const unsigned short* Qb = Qg + ((size_t)(b * 2048 + qt * 64)) * 512;
    const unsigned short* Kb = Kg + ((size_t)b * 2048) * 512;
    const unsigned short* Vb = VTg + ((size_t)b * 512) * 2048;

    // ---- stage Q (swizzled source) into Ks[0]
    #pragma unroll
    for (int i = 0; i < 4; i++) {
        int r = wid * 4 + i;
        gl_lds16(Qb + (size_t)r * 512 + ((lane ^ (r & 7)) * 8), &Ks[0][r * 512]);
    }
    __syncthreads();  // vmcnt(0): Q DMA done

    // st = union{ score: qf[16] (bf16x8 views) | PV: o[4][4] accumulators }
    f32x4 st[16];
    float accs[8];
    if (is_score) {
        int row = sqg * 16 + c;
        #pragma unroll
        for (int ks = 0; ks < 16; ks++)
            st[ks] = __builtin_bit_cast(f32x4,
                *(const bf16x8*)&Ks[0][row * 512 + (((ks * 4 + g) ^ (row & 7)) * 8)]);
    } else {
        const f32x4 fz = {0.f, 0.f, 0.f, 0.f};
        #pragma unroll
        for (int i = 0; i < 16; i++) st[i] = fz;
    }
    #pragma unroll
    for (int j = 0; j < 8; j++) accs[j] = 0.0f;
    __syncthreads();  // Q reads done before K(0) overwrites buf0

    // ---- stage K tile 0 into buf 0
    #pragma unroll
    for (int i = 0; i < 4; i++) {
        int r = wid * 4 + i;
        gl_lds16(Kb + (size_t)r * 512 + ((lane ^ (r & 7)) * 8), &Ks[0][r * 512]);
    }

    auto pv_step = [&](int tp) {
        const unsigned short* PsR = &Ps[tp & 1][0][0];
        bf16x8 bv[8];
        #pragma unroll
        for (int h = 0; h < 2; h++)
            #pragma unroll
            for (int ct = 0; ct < 4; ct++)
                bv[h * 4 + ct] = *(const bf16x8*)(Vb +
                    (size_t)(pcol + ct * 16 + c) * 2048 + tp * 64 + h * 32 + g * 8);
        #pragma unroll
        for (int h = 0; h < 2; h++)
            #pragma unroll
            for (int rt = 0; rt < 4; rt++) {
                bf16x8 pa = *(const bf16x8*)&PsR[(rt * 16 + c) * 72 + h * 32 + g * 8];
                #pragma unroll
                for (int ct = 0; ct < 4; ct++)
                    st[rt * 4 + ct] = __builtin_amdgcn_mfma_f32_16x16x32_bf16(
                        pa, bv[h * 4 + ct], st[rt * 4 + ct], 0, 0, 0);
            }
    };

    for (int t = 0; t < 32; t++) {
        __syncthreads();  // K(t) staged (vmcnt0); Ps(t-1) visible; Ps(t)-buf reads retired

        if (t + 1 < 32) {  // all waves stage K(t+1); DMA flies across this tile
            #pragma unroll
            for (int i = 0; i < 4; i++) {
                int r = wid * 4 + i;
                gl_lds16(Kb + (size_t)((t + 1) * 64 + r) * 512 + ((lane ^ (r & 7)) * 8),
                         &Ks[(t + 1) & 1][r * 512]);
            }
        }

        if (is_score) {
            const unsigned short* KsC = &Ks[t & 1][0];
            const f32x4 fz = {0.f, 0.f, 0.f, 0.f};
            f32x4 s0 = fz, s1 = fz;
            int kr0 = skg * 16 + c;
            int kr1 = kr0 + 16;
            #pragma unroll
            for (int ks = 0; ks < 16; ks++) {
                bf16x8 qv = __builtin_bit_cast(bf16x8, st[ks]);
                bf16x8 bk0 = *(const bf16x8*)&KsC[kr0 * 512 + (((ks * 4 + g) ^ (kr0 & 7)) * 8)];
                bf16x8 bk1 = *(const bf16x8*)&KsC[kr1 * 512 + (((ks * 4 + g) ^ (kr1 & 7)) * 8)];
                s0 = __builtin_amdgcn_mfma_f32_16x16x32_bf16(qv, bk0, s0, 0, 0, 0);
                s1 = __builtin_amdgcn_mfma_f32_16x16x32_bf16(qv, bk1, s1, 0, 0, 0);
            }
            unsigned short* PsW = &Ps[t & 1][0][0];
            #pragma unroll
            for (int r = 0; r < 4; r++) {
                int row = sqg * 16 + g * 4 + r;
                float p0 = __expf(s0[r]);
                float p1 = __expf(s1[r]);
                accs[r] += p0;
                accs[4 + r] += p1;
                PsW[row * 72 + skg * 16 + c] = f2bf(p0);
                PsW[row * 72 + (skg + 1) * 16 + c] = f2bf(p1);
            }
        } else if (t > 0) {
            pv_step(t - 1);
        }
    }

    // ---- score waves: final row-sum reduction into psum_s
    if (is_score) {
        #pragma unroll
        for (int r = 0; r < 4; r++) {
            float v = accs[r] + accs[4 + r];  // both kv-col groups of this wave
            v += __shfl_xor(v, 1);
            v += __shfl_xor(v, 2);
            v += __shfl_xor(v, 4);
            v += __shfl_xor(v, 8);
            if (c == 0) psum_s[sqg * 16 + g * 4 + r][wid & 1] = v;
        }
    }
    __syncthreads();  // Ps(31) + psum_s visible

    if (!is_score) {
        pv_step(31);
        float* ob = out + ((size_t)(b * 2048 + qt * 64)) * 512;
        #pragma unroll
        for (int rt = 0; rt < 4; rt++)
            #pragma unroll
            for (int r = 0; r < 4; r++) {
                int lrow = rt * 16 + g * 4 + r;
                float l = psum_s[lrow][0] + psum_s[lrow][1];
                float inv = 1.0f / l;
                #pragma unroll
                for (int ct = 0; ct < 4; ct++)
                    ob[(size_t)lrow * 512 + pcol + ct * 16 + c] = st[rt * 4 + ct][r] * inv;
            }
    }
}

// ---------------------------------------------------------------------------
extern "C" void kernel_launch(void* const* d_in, const int* in_sizes, int n_in,
                              void* d_out, int out_size, void* d_ws, size_t ws_size,
                              hipStream_t stream) {
    const float* x = (const float*)d_in[0];   // [8][2048][512] fp32
    const float* W = (const float*)d_in[1];   // [3][512][512] fp32
    float* out = (float*)d_out;               // [8][2048][512] fp32
    char* ws = (char*)d_ws;
    unsigned short* WT = (unsigned short*)(ws);
    unsigned short* Q  = (unsigned short*)(ws + (size_t)2  * 1024 * 1024);
    unsigned short* K  = (unsigned short*)(ws + (size_t)18 * 1024 * 1024);
    unsigned short* VT = (unsigned short*)(ws + (size_t)34 * 1024 * 1024);

    wt_kernel<<<192, 256, 0, stream>>>(W, WT);
    proj_kernel<<<1536, 256, 0, stream>>>(x, WT, Q, K, VT);
    attn_kernel<<<256, 1024, 0, stream>>>(Q, K, VT, out);
}

// Round 5
// 176.418 us; speedup vs baseline: 1.5670x; 1.2941x over previous
//
#include <hip/hip_runtime.h>
#include <hip/hip_bf16.h>

typedef __attribute__((ext_vector_type(8))) short bf16x8;
typedef __attribute__((ext_vector_type(4))) float f32x4;

#define DEV static __device__ __forceinline__

DEV unsigned short f2bf(float f) {
    union { __hip_bfloat16 h; unsigned short u; } cv;
    cv.h = __float2bfloat16(f);
    return cv.u;
}

typedef __attribute__((address_space(1))) const void gas_t;
typedef __attribute__((address_space(3))) void las_t;

DEV void gl_lds16(const unsigned short* g, unsigned short* l) {
    __builtin_amdgcn_global_load_lds((gas_t*)g, (las_t*)l, 16, 0, 0);
}

// ---------------------------------------------------------------------------
// Kernel 1: W [3][512][512] fp32 -> WT [3][512][512] bf16, transposed so the
// contraction dim (k) is fastest. W0 pre-scaled by 1/sqrt(512).
// ---------------------------------------------------------------------------
__global__ __launch_bounds__(256, 2) void wt_kernel(const float* __restrict__ W,
                                                    unsigned short* __restrict__ WT) {
    __shared__ __align__(16) unsigned short T[64][72];
    int bid = blockIdx.x;
    int w = bid >> 6;
    int rem = bid & 63;
    int kt = rem >> 3, nt = rem & 7;
    int t = threadIdx.x;
    int r = t >> 2, cq = t & 3;
    const float* src = W + ((size_t)(w * 512 + kt * 64 + r)) * 512 + nt * 64 + cq * 16;
    float sc = (w == 0) ? 0.04419417382415922f : 1.0f;  // 1/sqrt(512)
    #pragma unroll
    for (int i = 0; i < 4; i++) {
        float4 f = *(const float4*)(src + 4 * i);
        T[r][cq * 16 + 4 * i + 0] = f2bf(f.x * sc);
        T[r][cq * 16 + 4 * i + 1] = f2bf(f.y * sc);
        T[r][cq * 16 + 4 * i + 2] = f2bf(f.z * sc);
        T[r][cq * 16 + 4 * i + 3] = f2bf(f.w * sc);
    }
    __syncthreads();
    int n = t >> 2, kq = t & 3;
    bf16x8 v0, v1;
    #pragma unroll
    for (int e = 0; e < 8; e++) v0[e] = (short)T[kq * 16 + e][n];
    #pragma unroll
    for (int e = 0; e < 8; e++) v1[e] = (short)T[kq * 16 + 8 + e][n];
    unsigned short* dst = WT + ((size_t)(w * 512 + nt * 64 + n)) * 512 + kt * 64 + kq * 16;
    *(bf16x8*)dst = v0;
    *(bf16x8*)(dst + 8) = v1;
}

// ---------------------------------------------------------------------------
// Kernel 2: QKV projection (unchanged). Outputs Q,K row-major bf16;
// V transposed to VT [8][512][2048] bf16.
// ---------------------------------------------------------------------------
__global__ __launch_bounds__(256, 2) void proj_kernel(const float* __restrict__ x,
        const unsigned short* __restrict__ WT,
        unsigned short* __restrict__ Qo, unsigned short* __restrict__ Ko,
        unsigned short* __restrict__ VTo) {
    __shared__ __align__(16) unsigned short As[128][40];
    __shared__ __align__(16) unsigned short Bs[128][40];
    __shared__ __align__(16) unsigned short Cs[128][132];

    int bid = blockIdx.x;
    int swz = (bid & 7) * 192 + (bid >> 3);
    int mt = swz / 12;
    int rem = swz - mt * 12;
    int w = rem >> 2, nt = rem & 3;
    int tid = threadIdx.x;
    int lane = tid & 63, wid = tid >> 6;
    int wm = wid >> 1, wn = wid & 1;
    int c = lane & 15, g = lane >> 4;

    const f32x4 fz = {0.f, 0.f, 0.f, 0.f};
    f32x4 acc[4][4];
    #pragma unroll
    for (int i = 0; i < 4; i++)
        #pragma unroll
        for (int j = 0; j < 4; j++) acc[i][j] = fz;

    int srow = tid >> 1, kh = tid & 1;
    const float* xp = x + (size_t)(mt * 128 + srow) * 512 + kh * 16;
    const unsigned short* wp = WT + ((size_t)(w * 512 + nt * 128 + srow)) * 512 + kh * 16;

    for (int kk = 0; kk < 16; kk++) {
        {
            const float* p = xp + kk * 32;
            float4 f0 = *(const float4*)(p);
            float4 f1 = *(const float4*)(p + 4);
            float4 f2 = *(const float4*)(p + 8);
            float4 f3 = *(const float4*)(p + 12);
            bf16x8 u0, u1;
            u0[0] = (short)f2bf(f0.x); u0[1] = (short)f2bf(f0.y);
            u0[2] = (short)f2bf(f0.z); u0[3] = (short)f2bf(f0.w);
            u0[4] = (short)f2bf(f1.x); u0[5] = (short)f2bf(f1.y);
            u0[6] = (short)f2bf(f1.z); u0[7] = (short)f2bf(f1.w);
            u1[0] = (short)f2bf(f2.x); u1[1] = (short)f2bf(f2.y);
            u1[2] = (short)f2bf(f2.z); u1[3] = (short)f2bf(f2.w);
            u1[4] = (short)f2bf(f3.x); u1[5] = (short)f2bf(f3.y);
            u1[6] = (short)f2bf(f3.z); u1[7] = (short)f2bf(f3.w);
            *(bf16x8*)&As[srow][kh * 16] = u0;
            *(bf16x8*)&As[srow][kh * 16 + 8] = u1;
            const unsigned short* q = wp + kk * 32;
            *(bf16x8*)&Bs[srow][kh * 16] = *(const bf16x8*)q;
            *(bf16x8*)&Bs[srow][kh * 16 + 8] = *(const bf16x8*)(q + 8);
        }
        __syncthreads();
        bf16x8 a[4], bb[4];
        #pragma unroll
        for (int rt = 0; rt < 4; rt++) a[rt] = *(const bf16x8*)&As[wm * 64 + rt * 16 + c][g * 8];
        #pragma unroll
        for (int ct = 0; ct < 4; ct++) bb[ct] = *(const bf16x8*)&Bs[wn * 64 + ct * 16 + c][g * 8];
        #pragma unroll
        for (int rt = 0; rt < 4; rt++)
            #pragma unroll
            for (int ct = 0; ct < 4; ct++)
                acc[rt][ct] = __builtin_amdgcn_mfma_f32_16x16x32_bf16(a[rt], bb[ct], acc[rt][ct], 0, 0, 0);
        __syncthreads();
    }

    if (w < 2) {
        unsigned short* dst = (w == 0) ? Qo : Ko;
        #pragma unroll
        for (int rt = 0; rt < 4; rt++)
            #pragma unroll
            for (int ct = 0; ct < 4; ct++)
                #pragma unroll
                for (int r = 0; r < 4; r++) {
                    int grow = mt * 128 + wm * 64 + rt * 16 + g * 4 + r;
                    int gcol = nt * 128 + wn * 64 + ct * 16 + c;
                    dst[(size_t)grow * 512 + gcol] = f2bf(acc[rt][ct][r]);
                }
    } else {
        #pragma unroll
        for (int rt = 0; rt < 4; rt++)
            #pragma unroll
            for (int ct = 0; ct < 4; ct++)
                #pragma unroll
                for (int r = 0; r < 4; r++)
                    Cs[wm * 64 + rt * 16 + g * 4 + r][wn * 64 + ct * 16 + c] = f2bf(acc[rt][ct][r]);
        __syncthreads();
        int dcol = tid >> 1, sh = tid & 1;
        int bb2 = mt >> 4;
        int s0r = (mt & 15) * 128;
        #pragma unroll
        for (int jj = 0; jj < 8; jj++) {
            bf16x8 v;
            #pragma unroll
            for (int e = 0; e < 8; e++) v[e] = (short)Cs[sh * 64 + jj * 8 + e][dcol];
            *(bf16x8*)(VTo + ((size_t)(bb2 * 512 + nt * 128 + dcol)) * 2048 + s0r + sh * 64 + jj * 8) = v;
        }
    }
}

// ---------------------------------------------------------------------------
// Kernel 3 (v7): wave-specialized flash attention with SEPARATE role loops.
// v5/v6 failed because st[16] escaped into a by-reference lambda -> SROA
// couldn't promote it -> accumulators lived in scratch (VGPR=64, WRITE 139MB).
// Here: score waves (wid<8) and PV waves (wid>=8) run disjoint code paths
// with matching barrier counts (35 each). qf[16] is score-scope-only,
// o[16] is PV-scope-only; PV step is a _Pragma-unrolled macro (no lambda,
// no address escape, all-constant indices).
// ---------------------------------------------------------------------------
#define STAGE_K(tt) do {                                                        \
    _Pragma("unroll")                                                           \
    for (int i_ = 0; i_ < 4; i_++) {                                            \
        int r_ = wid * 4 + i_;                                                  \
        gl_lds16(Kb + (size_t)((tt) * 64 + r_) * 512 + ((lane ^ (r_ & 7)) * 8), \
                 &Ks[(tt) & 1][r_ * 512]);                                      \
    }                                                                           \
} while (0)

#define PV_BODY(tp) do {                                                        \
    const unsigned short* PsR_ = &Ps[(tp) & 1][0][0];                           \
    const unsigned short* Vp_ = Vb + (size_t)(pcol + c) * 2048 + (tp) * 64 + g * 8; \
    bf16x8 bv_[8];                                                              \
    _Pragma("unroll")                                                           \
    for (int h_ = 0; h_ < 2; h_++)                                              \
        _Pragma("unroll")                                                       \
        for (int ct_ = 0; ct_ < 4; ct_++)                                       \
            bv_[h_ * 4 + ct_] = *(const bf16x8*)(Vp_ + (size_t)(ct_ * 16) * 2048 + h_ * 32); \
    _Pragma("unroll")                                                           \
    for (int h_ = 0; h_ < 2; h_++)                                              \
        _Pragma("unroll")                                                       \
        for (int rt_ = 0; rt_ < 4; rt_++) {                                     \
            bf16x8 pa_ = *(const bf16x8*)&PsR_[(rt_ * 16 + c) * 72 + h_ * 32 + g * 8]; \
            _Pragma("unroll")                                                   \
            for (int ct_ = 0; ct_ < 4; ct_++)                                   \
                o[rt_ * 4 + ct_] = __builtin_amdgcn_mfma_f32_16x16x32_bf16(     \
                    pa_, bv_[h_ * 4 + ct_], o[rt_ * 4 + ct_], 0, 0, 0);         \
        }                                                                       \
} while (0)

__global__ __launch_bounds__(1024, 4) void attn_kernel(const unsigned short* __restrict__ Qg,
        const unsigned short* __restrict__ Kg, const unsigned short* __restrict__ VTg,
        float* __restrict__ out) {
    __shared__ __align__(16) unsigned short Ks[2][64 * 512];  // 128 KB, swizzled
    __shared__ __align__(16) unsigned short Ps[2][64][72];    // 18.4 KB, dbuf
    __shared__ float psum_s[64][2];

    int bid = blockIdx.x;
    int swz = (bid & 7) * 32 + (bid >> 3);  // XCD x owns batch x
    int b = swz >> 5, qt = swz & 31;
    int tid = threadIdx.x;
    int lane = tid & 63, wid = tid >> 6;    // wid 0..15
    int c = lane & 15, g = lane >> 4;

    const unsigned short* Qb = Qg + ((size_t)(b * 2048 + qt * 64)) * 512;
    const unsigned short* Kb = Kg + ((size_t)b * 2048) * 512;
    const unsigned short* Vb = VTg + ((size_t)b * 512) * 2048;

    // ---- stage Q (swizzled source) into Ks[0] — all waves
    #pragma unroll
    for (int i = 0; i < 4; i++) {
        int r = wid * 4 + i;
        gl_lds16(Qb + (size_t)r * 512 + ((lane ^ (r & 7)) * 8), &Ks[0][r * 512]);
    }

    if (wid < 8) {
        // ================= score waves =================
        int sqg = wid >> 1;          // q-row group (0..3), two waves each
        int skg = (wid & 1) * 2;     // first of two 16-col kv groups (0 or 2)
        __syncthreads();             // A: Q DMA done (vmcnt0)
        bf16x8 qf[16];
        {
            int row = sqg * 16 + c;
            #pragma unroll
            for (int ks = 0; ks < 16; ks++)
                qf[ks] = *(const bf16x8*)&Ks[0][row * 512 + (((ks * 4 + g) ^ (row & 7)) * 8)];
        }
        __syncthreads();             // B: Q reads done before K(0) overwrite
        STAGE_K(0);

        float accs[8];
        #pragma unroll
        for (int j = 0; j < 8; j++) accs[j] = 0.0f;

        for (int t = 0; t < 32; t++) {
            __syncthreads();         // K(t) staged; Ps(t) buffer free
            if (t + 1 < 32) STAGE_K(t + 1);

            const unsigned short* KsC = &Ks[t & 1][0];
            const f32x4 fz = {0.f, 0.f, 0.f, 0.f};
            f32x4 s0 = fz, s1 = fz;
            int kr0 = skg * 16 + c;
            int kr1 = kr0 + 16;
            #pragma unroll
            for (int ks = 0; ks < 16; ks++) {
                bf16x8 bk0 = *(const bf16x8*)&KsC[kr0 * 512 + (((ks * 4 + g) ^ (kr0 & 7)) * 8)];
                bf16x8 bk1 = *(const bf16x8*)&KsC[kr1 * 512 + (((ks * 4 + g) ^ (kr1 & 7)) * 8)];
                s0 = __builtin_amdgcn_mfma_f32_16x16x32_bf16(qf[ks], bk0, s0, 0, 0, 0);
                s1 = __builtin_amdgcn_mfma_f32_16x16x32_bf16(qf[ks], bk1, s1, 0, 0, 0);
            }
            unsigned short* PsW = &Ps[t & 1][0][0];
            #pragma unroll
            for (int r = 0; r < 4; r++) {
                int row = sqg * 16 + g * 4 + r;
                float p0 = __expf(s0[r]);
                float p1 = __expf(s1[r]);
                accs[r] += p0;
                accs[4 + r] += p1;
                PsW[row * 72 + skg * 16 + c] = f2bf(p0);
                PsW[row * 72 + (skg + 1) * 16 + c] = f2bf(p1);
            }
        }

        // final row-sum reduction into psum_s
        #pragma unroll
        for (int r = 0; r < 4; r++) {
            float v = accs[r] + accs[4 + r];
            v += __shfl_xor(v, 1);
            v += __shfl_xor(v, 2);
            v += __shfl_xor(v, 4);
            v += __shfl_xor(v, 8);
            if (c == 0) psum_s[sqg * 16 + g * 4 + r][wid & 1] = v;
        }
        __syncthreads();             // C: Ps(31) + psum_s published
    } else {
        // ================= PV waves =================
        int pcol = (wid - 8) * 64;   // d-column base (0..448)
        __syncthreads();             // A
        __syncthreads();             // B
        STAGE_K(0);

        f32x4 o[16];
        {
            const f32x4 fz = {0.f, 0.f, 0.f, 0.f};
            #pragma unroll
            for (int i = 0; i < 16; i++) o[i] = fz;
        }

        for (int t = 0; t < 32; t++) {
            __syncthreads();         // K(t) staged; Ps(t-1) visible
            if (t + 1 < 32) STAGE_K(t + 1);
            if (t > 0) PV_BODY(t - 1);
        }
        __syncthreads();             // C: Ps(31) + psum_s visible
        PV_BODY(31);

        float* ob = out + ((size_t)(b * 2048 + qt * 64)) * 512;
        #pragma unroll
        for (int rt = 0; rt < 4; rt++)
            #pragma unroll
            for (int r = 0; r < 4; r++) {
                int lrow = rt * 16 + g * 4 + r;
                float l = psum_s[lrow][0] + psum_s[lrow][1];
                float inv = 1.0f / l;
                #pragma unroll
                for (int ct = 0; ct < 4; ct++)
                    ob[(size_t)lrow * 512 + pcol + ct * 16 + c] = o[rt * 4 + ct][r] * inv;
            }
    }
}

// ---------------------------------------------------------------------------
extern "C" void kernel_launch(void* const* d_in, const int* in_sizes, int n_in,
                              void* d_out, int out_size, void* d_ws, size_t ws_size,
                              hipStream_t stream) {
    const float* x = (const float*)d_in[0];   // [8][2048][512] fp32
    const float* W = (const float*)d_in[1];   // [3][512][512] fp32
    float* out = (float*)d_out;               // [8][2048][512] fp32
    char* ws = (char*)d_ws;
    unsigned short* WT = (unsigned short*)(ws);
    unsigned short* Q  = (unsigned short*)(ws + (size_t)2  * 1024 * 1024);
    unsigned short* K  = (unsigned short*)(ws + (size_t)18 * 1024 * 1024);
    unsigned short* VT = (unsigned short*)(ws + (size_t)34 * 1024 * 1024);

    wt_kernel<<<192, 256, 0, stream>>>(W, WT);
    proj_kernel<<<1536, 256, 0, stream>>>(x, WT, Q, K, VT);
    attn_kernel<<<256, 1024, 0, stream>>>(Q, K, VT, out);
}

// Round 6
// 152.901 us; speedup vs baseline: 1.8080x; 1.1538x over previous
//
#include <hip/hip_runtime.h>
#include <hip/hip_bf16.h>

typedef __attribute__((ext_vector_type(8))) short bf16x8;
typedef __attribute__((ext_vector_type(4))) float f32x4;

#define DEV static __device__ __forceinline__

DEV unsigned short f2bf(float f) {
    union { __hip_bfloat16 h; unsigned short u; } cv;
    cv.h = __float2bfloat16(f);
    return cv.u;
}

typedef __attribute__((address_space(1))) const void gas_t;
typedef __attribute__((address_space(3))) void las_t;

DEV void gl_lds16(const unsigned short* g, unsigned short* l) {
    __builtin_amdgcn_global_load_lds((gas_t*)g, (las_t*)l, 16, 0, 0);
}

// ---------------------------------------------------------------------------
// Kernel 0: x [8][2048][512] fp32 -> xb bf16 (same layout). Done ONCE so proj
// blocks (12 readers per x-row-block) read 2B/elem with zero cvt VALU.
// xb lives in the OUTPUT buffer's first 16 MB (dead until attn's full
// overwrite at the very end).
// ---------------------------------------------------------------------------
__global__ __launch_bounds__(256) void xcvt_kernel(const float* __restrict__ x,
                                                   unsigned short* __restrict__ xb) {
    size_t i = ((size_t)blockIdx.x * 256 + threadIdx.x) * 8;
    float4 f0 = *(const float4*)(x + i);
    float4 f1 = *(const float4*)(x + i + 4);
    bf16x8 u;
    u[0] = (short)f2bf(f0.x); u[1] = (short)f2bf(f0.y);
    u[2] = (short)f2bf(f0.z); u[3] = (short)f2bf(f0.w);
    u[4] = (short)f2bf(f1.x); u[5] = (short)f2bf(f1.y);
    u[6] = (short)f2bf(f1.z); u[7] = (short)f2bf(f1.w);
    *(bf16x8*)(xb + i) = u;
}

// ---------------------------------------------------------------------------
// Kernel 1: W [3][512][512] fp32 -> WT [3][512][512] bf16, transposed so the
// contraction dim (k) is fastest. W0 pre-scaled by 1/sqrt(512).
// ---------------------------------------------------------------------------
__global__ __launch_bounds__(256, 2) void wt_kernel(const float* __restrict__ W,
                                                    unsigned short* __restrict__ WT) {
    __shared__ __align__(16) unsigned short T[64][72];
    int bid = blockIdx.x;
    int w = bid >> 6;
    int rem = bid & 63;
    int kt = rem >> 3, nt = rem & 7;
    int t = threadIdx.x;
    int r = t >> 2, cq = t & 3;
    const float* src = W + ((size_t)(w * 512 + kt * 64 + r)) * 512 + nt * 64 + cq * 16;
    float sc = (w == 0) ? 0.04419417382415922f : 1.0f;  // 1/sqrt(512)
    #pragma unroll
    for (int i = 0; i < 4; i++) {
        float4 f = *(const float4*)(src + 4 * i);
        T[r][cq * 16 + 4 * i + 0] = f2bf(f.x * sc);
        T[r][cq * 16 + 4 * i + 1] = f2bf(f.y * sc);
        T[r][cq * 16 + 4 * i + 2] = f2bf(f.z * sc);
        T[r][cq * 16 + 4 * i + 3] = f2bf(f.w * sc);
    }
    __syncthreads();
    int n = t >> 2, kq = t & 3;
    bf16x8 v0, v1;
    #pragma unroll
    for (int e = 0; e < 8; e++) v0[e] = (short)T[kq * 16 + e][n];
    #pragma unroll
    for (int e = 0; e < 8; e++) v1[e] = (short)T[kq * 16 + 8 + e][n];
    unsigned short* dst = WT + ((size_t)(w * 512 + nt * 64 + n)) * 512 + kt * 64 + kq * 16;
    *(bf16x8*)dst = v0;
    *(bf16x8*)(dst + 8) = v1;
}

// ---------------------------------------------------------------------------
// Kernel 2 (v8): QKV projection with global_load_lds staging of BOTH operands
// (bf16 x from xcvt). Double-buffered, 1 barrier per k-chunk (was 2), zero
// cvt/pack VALU in the loop. XOR-swizzled DMA source; reads use same XOR.
// LDS chunk layout: [128 rows][32 shorts]; pos p of row r holds global chunk
// p^(r&3) (16B chunks), so read chunk g at pos g^(r&3) -> 2-way max conflict.
// ---------------------------------------------------------------------------
#define STAGE_P(kk) do {                                                          \
    _Pragma("unroll")                                                             \
    for (int i_ = 0; i_ < 2; i_++) {                                              \
        int r_ = wid * 32 + i_ * 16 + (lane >> 2);                                \
        int ch_ = (lane & 3) ^ (r_ & 3);                                          \
        gl_lds16(xp + (size_t)r_ * 512 + (kk) * 32 + ch_ * 8,                     \
                 &As[(kk) & 1][(wid * 32 + i_ * 16) * 32]);                       \
        gl_lds16(wp + (size_t)r_ * 512 + (kk) * 32 + ch_ * 8,                     \
                 &Bs[(kk) & 1][(wid * 32 + i_ * 16) * 32]);                       \
    }                                                                             \
} while (0)

__global__ __launch_bounds__(256, 2) void proj_kernel(const unsigned short* __restrict__ xb,
        const unsigned short* __restrict__ WT,
        unsigned short* __restrict__ Qo, unsigned short* __restrict__ Ko,
        unsigned short* __restrict__ VTo) {
    __shared__ __align__(16) unsigned short As[2][128 * 32];  // 16 KB
    __shared__ __align__(16) unsigned short Bs[2][128 * 32];  // 16 KB
    __shared__ __align__(16) unsigned short Cs[128][132];     // 33.8 KB

    int bid = blockIdx.x;
    int swz = (bid & 7) * 192 + (bid >> 3);
    int mt = swz / 12;
    int rem = swz - mt * 12;
    int w = rem >> 2, nt = rem & 3;
    int tid = threadIdx.x;
    int lane = tid & 63, wid = tid >> 6;
    int wm = wid >> 1, wn = wid & 1;
    int c = lane & 15, g = lane >> 4;

    const unsigned short* xp = xb + (size_t)(mt * 128) * 512;
    const unsigned short* wp = WT + ((size_t)(w * 512 + nt * 128)) * 512;

    const f32x4 fz = {0.f, 0.f, 0.f, 0.f};
    f32x4 acc[4][4];
    #pragma unroll
    for (int i = 0; i < 4; i++)
        #pragma unroll
        for (int j = 0; j < 4; j++) acc[i][j] = fz;

    STAGE_P(0);
    for (int kk = 0; kk < 16; kk++) {
        __syncthreads();                 // buf[kk&1] DMA drained (vmcnt0)
        if (kk + 1 < 16) STAGE_P(kk + 1);
        const unsigned short* Ac = &As[kk & 1][0];
        const unsigned short* Bc = &Bs[kk & 1][0];
        bf16x8 a[4], bb[4];
        #pragma unroll
        for (int rt = 0; rt < 4; rt++) {
            int row = wm * 64 + rt * 16 + c;
            a[rt] = *(const bf16x8*)&Ac[row * 32 + ((g ^ (row & 3)) * 8)];
        }
        #pragma unroll
        for (int ct = 0; ct < 4; ct++) {
            int row = wn * 64 + ct * 16 + c;
            bb[ct] = *(const bf16x8*)&Bc[row * 32 + ((g ^ (row & 3)) * 8)];
        }
        #pragma unroll
        for (int rt = 0; rt < 4; rt++)
            #pragma unroll
            for (int ct = 0; ct < 4; ct++)
                acc[rt][ct] = __builtin_amdgcn_mfma_f32_16x16x32_bf16(a[rt], bb[ct], acc[rt][ct], 0, 0, 0);
    }

    if (w < 2) {
        unsigned short* dst = (w == 0) ? Qo : Ko;
        #pragma unroll
        for (int rt = 0; rt < 4; rt++)
            #pragma unroll
            for (int ct = 0; ct < 4; ct++)
                #pragma unroll
                for (int r = 0; r < 4; r++) {
                    int grow = mt * 128 + wm * 64 + rt * 16 + g * 4 + r;
                    int gcol = nt * 128 + wn * 64 + ct * 16 + c;
                    dst[(size_t)grow * 512 + gcol] = f2bf(acc[rt][ct][r]);
                }
    } else {
        #pragma unroll
        for (int rt = 0; rt < 4; rt++)
            #pragma unroll
            for (int ct = 0; ct < 4; ct++)
                #pragma unroll
                for (int r = 0; r < 4; r++)
                    Cs[wm * 64 + rt * 16 + g * 4 + r][wn * 64 + ct * 16 + c] = f2bf(acc[rt][ct][r]);
        __syncthreads();
        int dcol = tid >> 1, sh = tid & 1;
        int bb2 = mt >> 4;
        int s0r = (mt & 15) * 128;
        #pragma unroll
        for (int jj = 0; jj < 8; jj++) {
            bf16x8 v;
            #pragma unroll
            for (int e = 0; e < 8; e++) v[e] = (short)Cs[sh * 64 + jj * 8 + e][dcol];
            *(bf16x8*)(VTo + ((size_t)(bb2 * 512 + nt * 128 + dcol)) * 2048 + s0r + sh * 64 + jj * 8) = v;
        }
    }
}

// ---------------------------------------------------------------------------
// Kernel 3 (v8): wave-specialized flash attention (v7 structure) + PV V-tile
// prefetch: first half of V(t) is loaded one tile ahead into persistent regs
// (bva, 16 VGPRs); second half (bvb) issued before the h0 MFMAs so its L2
// latency hides under them. Removes ~300cyc exposed V latency per tile.
// ---------------------------------------------------------------------------
#define STAGE_K(tt) do {                                                        \
    _Pragma("unroll")                                                           \
    for (int i_ = 0; i_ < 4; i_++) {                                            \
        int r_ = wid * 4 + i_;                                                  \
        gl_lds16(Kb + (size_t)((tt) * 64 + r_) * 512 + ((lane ^ (r_ & 7)) * 8), \
                 &Ks[(tt) & 1][r_ * 512]);                                      \
    }                                                                           \
} while (0)

__global__ __launch_bounds__(1024, 4) void attn_kernel(const unsigned short* __restrict__ Qg,
        const unsigned short* __restrict__ Kg, const unsigned short* __restrict__ VTg,
        float* __restrict__ out) {
    __shared__ __align__(16) unsigned short Ks[2][64 * 512];  // 128 KB, swizzled
    __shared__ __align__(16) unsigned short Ps[2][64][72];    // 18.4 KB, dbuf
    __shared__ float psum_s[64][2];

    int bid = blockIdx.x;
    int swz = (bid & 7) * 32 + (bid >> 3);  // XCD x owns batch x
    int b = swz >> 5, qt = swz & 31;
    int tid = threadIdx.x;
    int lane = tid & 63, wid = tid >> 6;    // wid 0..15
    int c = lane & 15, g = lane >> 4;

    const unsigned short* Qb = Qg + ((size_t)(b * 2048 + qt * 64)) * 512;
    const unsigned short* Kb = Kg + ((size_t)b * 2048) * 512;
    const unsigned short* Vb = VTg + ((size_t)b * 512) * 2048;

    // ---- stage Q (swizzled source) into Ks[0] — all waves
    #pragma unroll
    for (int i = 0; i < 4; i++) {
        int r = wid * 4 + i;
        gl_lds16(Qb + (size_t)r * 512 + ((lane ^ (r & 7)) * 8), &Ks[0][r * 512]);
    }

    if (wid < 8) {
        // ================= score waves =================
        int sqg = wid >> 1;          // q-row group (0..3), two waves each
        int skg = (wid & 1) * 2;     // first of two 16-col kv groups (0 or 2)
        __syncthreads();             // A: Q DMA done (vmcnt0)
        bf16x8 qf[16];
        {
            int row = sqg * 16 + c;
            #pragma unroll
            for (int ks = 0; ks < 16; ks++)
                qf[ks] = *(const bf16x8*)&Ks[0][row * 512 + (((ks * 4 + g) ^ (row & 7)) * 8)];
        }
        __syncthreads();             // B: Q reads done before K(0) overwrite
        STAGE_K(0);

        float accs[8];
        #pragma unroll
        for (int j = 0; j < 8; j++) accs[j] = 0.0f;

        for (int t = 0; t < 32; t++) {
            __syncthreads();         // K(t) staged; Ps(t) buffer free
            if (t + 1 < 32) STAGE_K(t + 1);

            const unsigned short* KsC = &Ks[t & 1][0];
            const f32x4 fz = {0.f, 0.f, 0.f, 0.f};
            f32x4 s0 = fz, s1 = fz;
            int kr0 = skg * 16 + c;
            int kr1 = kr0 + 16;
            #pragma unroll
            for (int ks = 0; ks < 16; ks++) {
                bf16x8 bk0 = *(const bf16x8*)&KsC[kr0 * 512 + (((ks * 4 + g) ^ (kr0 & 7)) * 8)];
                bf16x8 bk1 = *(const bf16x8*)&KsC[kr1 * 512 + (((ks * 4 + g) ^ (kr1 & 7)) * 8)];
                s0 = __builtin_amdgcn_mfma_f32_16x16x32_bf16(qf[ks], bk0, s0, 0, 0, 0);
                s1 = __builtin_amdgcn_mfma_f32_16x16x32_bf16(qf[ks], bk1, s1, 0, 0, 0);
            }
            unsigned short* PsW = &Ps[t & 1][0][0];
            #pragma unroll
            for (int r = 0; r < 4; r++) {
                int row = sqg * 16 + g * 4 + r;
                float p0 = __expf(s0[r]);
                float p1 = __expf(s1[r]);
                accs[r] += p0;
                accs[4 + r] += p1;
                PsW[row * 72 + skg * 16 + c] = f2bf(p0);
                PsW[row * 72 + (skg + 1) * 16 + c] = f2bf(p1);
            }
        }

        // final row-sum reduction into psum_s
        #pragma unroll
        for (int r = 0; r < 4; r++) {
            float v = accs[r] + accs[4 + r];
            v += __shfl_xor(v, 1);
            v += __shfl_xor(v, 2);
            v += __shfl_xor(v, 4);
            v += __shfl_xor(v, 8);
            if (c == 0) psum_s[sqg * 16 + g * 4 + r][wid & 1] = v;
        }
        __syncthreads();             // C: Ps(31) + psum_s published
    } else {
        // ================= PV waves =================
        int pcol = (wid - 8) * 64;   // d-column base (0..448)
        const unsigned short* Vp = Vb + (size_t)(pcol + c) * 2048 + g * 8;
        __syncthreads();             // A
        __syncthreads();             // B
        STAGE_K(0);

        f32x4 o[16];
        {
            const f32x4 fz = {0.f, 0.f, 0.f, 0.f};
            #pragma unroll
            for (int i = 0; i < 16; i++) o[i] = fz;
        }
        bf16x8 bva[4];               // V(t, h0) prefetched one tile ahead
        #pragma unroll
        for (int ct = 0; ct < 4; ct++)
            bva[ct] = *(const bf16x8*)(Vp + (size_t)(ct * 16) * 2048);

        for (int t = 0; t < 32; t++) {
            __syncthreads();         // K(t) staged; Ps(t-1) visible
            if (t + 1 < 32) STAGE_K(t + 1);
            if (t > 0) {
                int tp = t - 1;
                const unsigned short* PsR = &Ps[tp & 1][0][0];
                bf16x8 bvb[4];       // V(tp, h1): issue now, use after h0 MFMAs
                #pragma unroll
                for (int ct = 0; ct < 4; ct++)
                    bvb[ct] = *(const bf16x8*)(Vp + (size_t)(ct * 16) * 2048 + tp * 64 + 32);
                #pragma unroll
                for (int rt = 0; rt < 4; rt++) {
                    bf16x8 pa = *(const bf16x8*)&PsR[(rt * 16 + c) * 72 + g * 8];
                    #pragma unroll
                    for (int ct = 0; ct < 4; ct++)
                        o[rt * 4 + ct] = __builtin_amdgcn_mfma_f32_16x16x32_bf16(
                            pa, bva[ct], o[rt * 4 + ct], 0, 0, 0);
                }
                #pragma unroll
                for (int ct = 0; ct < 4; ct++)   // prefetch V(t, h0) for next tile
                    bva[ct] = *(const bf16x8*)(Vp + (size_t)(ct * 16) * 2048 + t * 64);
                #pragma unroll
                for (int rt = 0; rt < 4; rt++) {
                    bf16x8 pa = *(const bf16x8*)&PsR[(rt * 16 + c) * 72 + 32 + g * 8];
                    #pragma unroll
                    for (int ct = 0; ct < 4; ct++)
                        o[rt * 4 + ct] = __builtin_amdgcn_mfma_f32_16x16x32_bf16(
                            pa, bvb[ct], o[rt * 4 + ct], 0, 0, 0);
                }
            }
        }
        __syncthreads();             // C: Ps(31) + psum_s visible
        {
            const unsigned short* PsR = &Ps[31 & 1][0][0];
            bf16x8 bvb[4];
            #pragma unroll
            for (int ct = 0; ct < 4; ct++)
                bvb[ct] = *(const bf16x8*)(Vp + (size_t)(ct * 16) * 2048 + 31 * 64 + 32);
            #pragma unroll
            for (int rt = 0; rt < 4; rt++) {
                bf16x8 pa = *(const bf16x8*)&PsR[(rt * 16 + c) * 72 + g * 8];
                #pragma unroll
                for (int ct = 0; ct < 4; ct++)
                    o[rt * 4 + ct] = __builtin_amdgcn_mfma_f32_16x16x32_bf16(
                        pa, bva[ct], o[rt * 4 + ct], 0, 0, 0);
            }
            #pragma unroll
            for (int rt = 0; rt < 4; rt++) {
                bf16x8 pa = *(const bf16x8*)&PsR[(rt * 16 + c) * 72 + 32 + g * 8];
                #pragma unroll
                for (int ct = 0; ct < 4; ct++)
                    o[rt * 4 + ct] = __builtin_amdgcn_mfma_f32_16x16x32_bf16(
                        pa, bvb[ct], o[rt * 4 + ct], 0, 0, 0);
            }
        }

        float* ob = out + ((size_t)(b * 2048 + qt * 64)) * 512;
        #pragma unroll
        for (int rt = 0; rt < 4; rt++)
            #pragma unroll
            for (int r = 0; r < 4; r++) {
                int lrow = rt * 16 + g * 4 + r;
                float l = psum_s[lrow][0] + psum_s[lrow][1];
                float inv = 1.0f / l;
                #pragma unroll
                for (int ct = 0; ct < 4; ct++)
                    ob[(size_t)lrow * 512 + pcol + ct * 16 + c] = o[rt * 4 + ct][r] * inv;
            }
    }
}

// ---------------------------------------------------------------------------
extern "C" void kernel_launch(void* const* d_in, const int* in_sizes, int n_in,
                              void* d_out, int out_size, void* d_ws, size_t ws_size,
                              hipStream_t stream) {
    const float* x = (const float*)d_in[0];   // [8][2048][512] fp32
    const float* W = (const float*)d_in[1];   // [3][512][512] fp32
    float* out = (float*)d_out;               // [8][2048][512] fp32
    char* ws = (char*)d_ws;
    unsigned short* WT = (unsigned short*)(ws);
    unsigned short* Q  = (unsigned short*)(ws + (size_t)2  * 1024 * 1024);
    unsigned short* K  = (unsigned short*)(ws + (size_t)18 * 1024 * 1024);
    unsigned short* VT = (unsigned short*)(ws + (size_t)34 * 1024 * 1024);
    // x-bf16 scratch lives in the OUTPUT buffer (16.7 MB of 33.5 MB); it is
    // fully dead before attn_kernel overwrites every element of out.
    unsigned short* xb = (unsigned short*)d_out;

    xcvt_kernel<<<4096, 256, 0, stream>>>(x, xb);
    wt_kernel<<<192, 256, 0, stream>>>(W, WT);
    proj_kernel<<<1536, 256, 0, stream>>>(xb, WT, Q, K, VT);
    attn_kernel<<<256, 1024, 0, stream>>>(Q, K, VT, out);
}